// Round 13
// baseline (1103.720 us; speedup 1.0000x reference)
//
#include <hip/hip_runtime.h>
#include <math.h>

#define N_NODES 50000
#define N_EDGES 1600000
#define NBATCH  64
#define INCH    128
#define HEADS   8
#define HD      8
#define GH      64
#define HIDDEN  64
#define NC      10
#define NEG_SLOPE 0.2f
#define BN_EPS  1e-5f

#define SCAN_TPB 1024
#define NTILES   ((N_NODES + SCAN_TPB - 1) / SCAN_TPB)   // 49

typedef unsigned short ushort_t;
typedef unsigned int uint_t;

__device__ __forceinline__ ushort_t f2bf(float f) {
  uint_t u = __float_as_uint(f);
  uint_t r = (u + 0x7fffu + ((u >> 16) & 1u)) >> 16;   // RNE
  return (ushort_t)r;
}
__device__ __forceinline__ float2 upk(uint_t u) {
  return make_float2(__uint_as_float(u << 16), __uint_as_float(u & 0xffff0000u));
}

// ---------------- edge pass ----------------
__global__ __launch_bounds__(256) void edge_kernel(
    const int* __restrict__ ei, const float* __restrict__ raw,
    float* __restrict__ ea, float* __restrict__ easum, int* __restrict__ cnt) {
  int e = blockIdx.x * blockDim.x + threadIdx.x;
  if (e >= N_EDGES) return;
  int s = ei[e], d = ei[N_EDGES + e];
  float dx = raw[s*3+0] - raw[d*3+0];
  float dy = raw[s*3+1] - raw[d*3+1];
  float dz = raw[s*3+2] - raw[d*3+2];
  float w = __expf(-2.0f * (dx*dx + dy*dy + dz*dz));
  ea[e] = w;
  atomicAdd(&easum[d], w);
  atomicAdd(&cnt[d], 1);
}

// ---------------- CSR build ----------------
__global__ __launch_bounds__(SCAN_TPB) void scan_part(
    const int* __restrict__ cnt, const float* __restrict__ easum,
    int* __restrict__ rowptr, float* __restrict__ loopat, int* __restrict__ bsum) {
  __shared__ int s[SCAN_TPB];
  int t = threadIdx.x;
  int i = blockIdx.x * SCAN_TPB + t;
  int v = (i < N_NODES) ? cnt[i] : 0;
  s[t] = v; __syncthreads();
  for (int off = 1; off < SCAN_TPB; off <<= 1) {
    int u = (t >= off) ? s[t - off] : 0;
    __syncthreads();
    s[t] += u;
    __syncthreads();
  }
  if (i < N_NODES) {
    rowptr[i] = s[t] - v;
    loopat[i] = easum[i] / fmaxf((float)v, 1.0f);
  }
  if (t == SCAN_TPB - 1) bsum[blockIdx.x] = s[t];
}

__global__ __launch_bounds__(64) void scan_top(int* __restrict__ bsum, int* __restrict__ rowptr) {
  int t = threadIdx.x;
  int v = (t < NTILES) ? bsum[t] : 0;
  int orig = v;
  for (int off = 1; off < 64; off <<= 1) {
    int u = __shfl_up(v, off);
    if (t >= off) v += u;
  }
  if (t < NTILES) bsum[t] = v - orig;
  if (t == 0) rowptr[N_NODES] = N_EDGES;
}

__global__ __launch_bounds__(SCAN_TPB) void scan_add(int* __restrict__ rowptr, const int* __restrict__ bsum) {
  int i = blockIdx.x * SCAN_TPB + threadIdx.x;
  if (i < N_NODES) rowptr[i] += bsum[blockIdx.x];
}

__global__ __launch_bounds__(256) void scatter_kernel(
    const int* __restrict__ ei, const float* __restrict__ ea,
    const int* __restrict__ rowptr, int* __restrict__ cnt2,
    int* __restrict__ csr_src, float* __restrict__ csr_ea) {
  int e = blockIdx.x * blockDim.x + threadIdx.x;
  if (e >= N_EDGES) return;
  int s = ei[e], d = ei[N_EDGES + e];
  int pos = rowptr[d] + atomicAdd(&cnt2[d], 1);
  csr_src[pos] = s;
  csr_ea[pos] = ea[e];
}

// ---------------- GEMM1: h1 = x @ W1 -> split bf16 half-tables + fused als1/ald1 --------
__global__ __launch_bounds__(256) void gemm1_kernel(
    const float* __restrict__ x, const float* __restrict__ W1,
    const float* __restrict__ asrc, const float* __restrict__ adst,
    ushort_t* __restrict__ tabLo, ushort_t* __restrict__ tabHi,
    float* __restrict__ als, float* __restrict__ ald) {
  __shared__ float w[INCH * GH];   // 32 KB
  for (int i = threadIdx.x; i < INCH * GH / 4; i += blockDim.x)
    ((float4*)w)[i] = ((const float4*)W1)[i];
  __syncthreads();
  int lane = threadIdx.x & 63;
  int waveG = __builtin_amdgcn_readfirstlane((blockIdx.x * blockDim.x + threadIdx.x) >> 6);
  int nWaves = (gridDim.x * blockDim.x) >> 6;
  float a_s = asrc[lane];
  float a_d = adst[lane];
  for (int base = waveG * 4; base < N_NODES; base += nWaves * 4) {   // N % 4 == 0
    float acc[4] = {0.f, 0.f, 0.f, 0.f};
    #pragma unroll 8
    for (int k = 0; k < INCH; ++k) {
      float wv = w[k * GH + lane];
      #pragma unroll
      for (int j = 0; j < 4; ++j)
        acc[j] = fmaf(x[(size_t)(base + j) * INCH + k], wv, acc[j]);
    }
    #pragma unroll
    for (int j = 0; j < 4; ++j) {
      int n = base + j;
      float hv = acc[j];
      ushort_t hb = f2bf(hv);
      if (lane < 32) tabLo[(size_t)n * 32 + lane] = hb;
      else           tabHi[(size_t)n * 32 + (lane - 32)] = hb;
      float ps = hv * a_s, pd = hv * a_d;
      ps += __shfl_xor(ps, 1); ps += __shfl_xor(ps, 2); ps += __shfl_xor(ps, 4);
      pd += __shfl_xor(pd, 1); pd += __shfl_xor(pd, 2); pd += __shfl_xor(pd, 4);
      if ((lane & 7) == 0) {
        als[n * HEADS + (lane >> 3)] = ps;
        ald[n * HEADS + (lane >> 3)] = pd;
      }
    }
  }
}

// ---------------- conv1 half-pass: heads H*4..H*4+3 over a 3.2MB half-table ------------
// Head-block-diagonal split: this pass's logits, softmax, and output dims are fully
// independent of the other half. lane = 8*oct + i8; oct handles edge slot g*8+oct;
// lane i8 covers half-dims 4*i8..4*i8+3 (global dims H*32+4*i8..), head = H*4 + (i8>>1).
__global__ __launch_bounds__(256) void conv1_half_kernel(
    const ushort_t* __restrict__ tab, const float* __restrict__ als,
    const float* __restrict__ ald,
    const float* __restrict__ We, const float* __restrict__ ae,
    const int* __restrict__ rowptr,
    const int* __restrict__ csr_src, const float* __restrict__ csr_ea,
    const float* __restrict__ loopat, const float* __restrict__ bias,
    const float* __restrict__ gamma, const float* __restrict__ beta,
    const float* __restrict__ rm, const float* __restrict__ rv,
    float* __restrict__ h2, int H) {
  __shared__ int   src_lds[4][64];
  __shared__ float ea_lds[4][64];
  int l = threadIdx.x & 63;
  int w = threadIdx.x >> 6;
  int n = blockIdx.x * 4 + w;
  if (n >= N_NODES) return;
  int i8 = l & 7;
  int oct = l >> 3;
  int fidx = H * 8 + i8;               // float4 index into 64-dim param vectors
  int head = H * 4 + (i8 >> 1);
  float4 we4 = ((const float4*)We)[fidx];
  float4 ae4 = ((const float4*)ae)[fidx];
  float ce = we4.x*ae4.x + we4.y*ae4.y + we4.z*ae4.z + we4.w*ae4.w;
  ce += __shfl_xor(ce, 1);             // per-head (pair of lanes) edge coeff
  float aldn     = ald[(size_t)n * HEADS + head];
  float als_self = als[(size_t)n * HEADS + head];
  const uint2* tb = (const uint2*)tab; // half-row = 8 x uint2 (64B)
  uint2 uself = tb[(size_t)n * 8 + i8];
  float2 s01 = upk(uself.x), s23 = upk(uself.y);
  int jb = rowptr[n], je = rowptr[n + 1];
  float ssum = 0.f;
  float a0 = 0.f, a1 = 0.f, a2 = 0.f, a3 = 0.f;

#define CH1_LOADG(G, R, A, E)                                          \
  {                                                                    \
    int jj = (G) * 8 + oct;                                            \
    bool vv = jj < cnt;                                                \
    int ss = vv ? src_lds[w][jj] : 0;                                  \
    R = tb[(size_t)ss * 8 + i8];                                       \
    A = vv ? als[(size_t)ss * HEADS + head] : -1e30f;                  \
    E = vv ? ea_lds[w][jj] : 0.f;                                      \
  }
#define CH1_PROC(R, A, E)                                              \
  {                                                                    \
    float2 t01 = upk(R.x), t23 = upk(R.y);                             \
    float lg = A + aldn + E * ce;                                      \
    lg = (lg >= 0.f) ? lg : NEG_SLOPE * lg;                            \
    float p = __expf(fminf(lg, 60.f));                                 \
    ssum += p;                                                         \
    a0 = fmaf(p, t01.x, a0); a1 = fmaf(p, t01.y, a1);                  \
    a2 = fmaf(p, t23.x, a2); a3 = fmaf(p, t23.y, a3);                  \
  }

  for (int cb = jb; cb < je; cb += 64) {
    int cnt = je - cb; if (cnt > 64) cnt = 64;
    src_lds[w][l] = (l < cnt) ? csr_src[cb + l] : 0;
    ea_lds[w][l]  = (l < cnt) ? csr_ea[cb + l] : 0.f;
    int ng = (cnt + 7) >> 3;
    uint2 rA, rB; float aA, aB, eA, eB;
    CH1_LOADG(0, rA, aA, eA)
    for (int g = 0; g < ng; g += 2) {
      bool hasB = (g + 1) < ng;
      if (hasB) CH1_LOADG(g + 1, rB, aB, eB)
      CH1_PROC(rA, aA, eA)
      if (hasB) {
        if (g + 2 < ng) CH1_LOADG(g + 2, rA, aA, eA)
        CH1_PROC(rB, aB, eB)
      }
    }
  }
#undef CH1_LOADG
#undef CH1_PROC

  // fold across octs (8 edge slots)
  ssum += __shfl_xor(ssum, 8); ssum += __shfl_xor(ssum, 16); ssum += __shfl_xor(ssum, 32);
  a0 += __shfl_xor(a0, 8); a0 += __shfl_xor(a0, 16); a0 += __shfl_xor(a0, 32);
  a1 += __shfl_xor(a1, 8); a1 += __shfl_xor(a1, 16); a1 += __shfl_xor(a1, 32);
  a2 += __shfl_xor(a2, 8); a2 += __shfl_xor(a2, 16); a2 += __shfl_xor(a2, 32);
  a3 += __shfl_xor(a3, 8); a3 += __shfl_xor(a3, 16); a3 += __shfl_xor(a3, 32);
  // self loop — AFTER fold
  {
    float lg = als_self + aldn + loopat[n] * ce;
    lg = (lg >= 0.f) ? lg : NEG_SLOPE * lg;
    float p = __expf(fminf(lg, 60.f));
    ssum += p;
    a0 = fmaf(p, s01.x, a0); a1 = fmaf(p, s01.y, a1);
    a2 = fmaf(p, s23.x, a2); a3 = fmaf(p, s23.y, a3);
  }
  if (oct == 0) {
    float inv = 1.0f / ssum;
    float4 b4 = ((const float4*)bias)[fidx];
    float4 g4 = ((const float4*)gamma)[fidx];
    float4 be4 = ((const float4*)beta)[fidx];
    float4 rm4 = ((const float4*)rm)[fidx];
    float4 rv4 = ((const float4*)rv)[fidx];
    float o0 = a0 * inv + b4.x, o1 = a1 * inv + b4.y;
    float o2 = a2 * inv + b4.z, o3 = a3 * inv + b4.w;
    o0 = (o0 - rm4.x) * (g4.x * rsqrtf(rv4.x + BN_EPS)) + be4.x;
    o1 = (o1 - rm4.y) * (g4.y * rsqrtf(rv4.y + BN_EPS)) + be4.y;
    o2 = (o2 - rm4.z) * (g4.z * rsqrtf(rv4.z + BN_EPS)) + be4.z;
    o3 = (o3 - rm4.w) * (g4.w * rsqrtf(rv4.w + BN_EPS)) + be4.w;
    o0 = (o0 > 0.f) ? o0 : expm1f(o0);
    o1 = (o1 > 0.f) ? o1 : expm1f(o1);
    o2 = (o2 > 0.f) ? o2 : expm1f(o2);
    o3 = (o3 > 0.f) ? o3 : expm1f(o3);
    ((float4*)(h2 + (size_t)n * GH))[fidx] = make_float4(o0, o1, o2, o3);
  }
}

// ---------------- GEMM2: h2m = h2 @ W2 -> split bf16 half-tables + fused als2/ald2 ------
__global__ __launch_bounds__(256) void gemm2_kernel(
    const float* __restrict__ x, const float* __restrict__ W2,
    const float* __restrict__ asrc, const float* __restrict__ adst,
    ushort_t* __restrict__ tabLo, ushort_t* __restrict__ tabHi,
    float* __restrict__ als, float* __restrict__ ald) {
  __shared__ float w[HIDDEN * HIDDEN];   // 16 KB
  for (int i = threadIdx.x; i < HIDDEN * HIDDEN / 4; i += blockDim.x)
    ((float4*)w)[i] = ((const float4*)W2)[i];
  __syncthreads();
  int lane = threadIdx.x & 63;
  int waveG = __builtin_amdgcn_readfirstlane((blockIdx.x * blockDim.x + threadIdx.x) >> 6);
  int nWaves = (gridDim.x * blockDim.x) >> 6;
  float a_s = asrc[lane];
  float a_d = adst[lane];
  for (int base = waveG * 4; base < N_NODES; base += nWaves * 4) {
    float acc[4] = {0.f, 0.f, 0.f, 0.f};
    #pragma unroll 8
    for (int k = 0; k < HIDDEN; ++k) {
      float wv = w[k * HIDDEN + lane];
      #pragma unroll
      for (int j = 0; j < 4; ++j)
        acc[j] = fmaf(x[(size_t)(base + j) * HIDDEN + k], wv, acc[j]);
    }
    #pragma unroll
    for (int j = 0; j < 4; ++j) {
      int n = base + j;
      float hv = acc[j];
      ushort_t hb = f2bf(hv);
      if (lane < 32) tabLo[(size_t)n * 32 + lane] = hb;
      else           tabHi[(size_t)n * 32 + (lane - 32)] = hb;
      float ps = hv * a_s, pd = hv * a_d;
      #pragma unroll
      for (int off = 1; off < 64; off <<= 1) {
        ps += __shfl_xor(ps, off);
        pd += __shfl_xor(pd, off);
      }
      if (lane == 0) { als[n] = ps; ald[n] = pd; }
    }
  }
}

// ---------------- conv2 half-pass (heads=1): dims H*32..H*32+31 ------------------------
// p is recomputed identically in both passes from precomputed als2/ald2 (no handoff).
__global__ __launch_bounds__(256) void conv2_half_kernel(
    const ushort_t* __restrict__ tab, const float* __restrict__ als,
    const float* __restrict__ ald,
    const float* __restrict__ We, const float* __restrict__ ae,
    const int* __restrict__ rowptr,
    const int* __restrict__ csr_src, const float* __restrict__ csr_ea,
    const float* __restrict__ loopat, const float* __restrict__ bias,
    const float* __restrict__ gamma, const float* __restrict__ beta,
    const float* __restrict__ rm, const float* __restrict__ rv,
    const int* __restrict__ batch,
    float* __restrict__ pool, int* __restrict__ cntg, int H) {
  __shared__ int   src_lds[4][64];
  __shared__ float ea_lds[4][64];
  int l = threadIdx.x & 63;
  int w = threadIdx.x >> 6;
  int n = blockIdx.x * 4 + w;
  if (n >= N_NODES) return;
  int i8 = l & 7;
  int oct = l >> 3;
  int fidx = H * 8 + i8;
  // full 64-dim edge coeff: each of the 8 lanes in an oct covers 2 float4s
  float4 wa = ((const float4*)We)[i8];
  float4 aa = ((const float4*)ae)[i8];
  float4 wb = ((const float4*)We)[i8 + 8];
  float4 ab = ((const float4*)ae)[i8 + 8];
  float ce = wa.x*aa.x + wa.y*aa.y + wa.z*aa.z + wa.w*aa.w
           + wb.x*ab.x + wb.y*ab.y + wb.z*ab.z + wb.w*ab.w;
  ce += __shfl_xor(ce, 1); ce += __shfl_xor(ce, 2); ce += __shfl_xor(ce, 4);
  float aldn     = ald[n];
  float als_self = als[n];
  const uint2* tb = (const uint2*)tab;   // half-row = 8 x uint2 (64B)
  uint2 uself = tb[(size_t)n * 8 + i8];
  float2 s01 = upk(uself.x), s23 = upk(uself.y);
  int jb = rowptr[n], je = rowptr[n + 1];
  float ssum = 0.f;
  float a0 = 0.f, a1 = 0.f, a2 = 0.f, a3 = 0.f;

#define CH2_LOADG(G, R, A, E)                                          \
  {                                                                    \
    int jj = (G) * 8 + oct;                                            \
    bool vv = jj < cnt;                                                \
    int ss = vv ? src_lds[w][jj] : 0;                                  \
    R = tb[(size_t)ss * 8 + i8];                                       \
    A = vv ? als[ss] : -1e30f;                                         \
    E = vv ? ea_lds[w][jj] : 0.f;                                      \
  }
#define CH2_PROC(R, A, E)                                              \
  {                                                                    \
    float2 t01 = upk(R.x), t23 = upk(R.y);                             \
    float lg = A + aldn + E * ce;                                      \
    lg = (lg >= 0.f) ? lg : NEG_SLOPE * lg;                            \
    float p = __expf(fminf(lg, 60.f));                                 \
    ssum += p;                                                         \
    a0 = fmaf(p, t01.x, a0); a1 = fmaf(p, t01.y, a1);                  \
    a2 = fmaf(p, t23.x, a2); a3 = fmaf(p, t23.y, a3);                  \
  }

  for (int cb = jb; cb < je; cb += 64) {
    int cnt = je - cb; if (cnt > 64) cnt = 64;
    src_lds[w][l] = (l < cnt) ? csr_src[cb + l] : 0;
    ea_lds[w][l]  = (l < cnt) ? csr_ea[cb + l] : 0.f;
    int ng = (cnt + 7) >> 3;
    uint2 rA, rB; float aA, aB, eA, eB;
    CH2_LOADG(0, rA, aA, eA)
    for (int g = 0; g < ng; g += 2) {
      bool hasB = (g + 1) < ng;
      if (hasB) CH2_LOADG(g + 1, rB, aB, eB)
      CH2_PROC(rA, aA, eA)
      if (hasB) {
        if (g + 2 < ng) CH2_LOADG(g + 2, rA, aA, eA)
        CH2_PROC(rB, aB, eB)
      }
    }
  }
#undef CH2_LOADG
#undef CH2_PROC

  ssum += __shfl_xor(ssum, 8); ssum += __shfl_xor(ssum, 16); ssum += __shfl_xor(ssum, 32);
  a0 += __shfl_xor(a0, 8); a0 += __shfl_xor(a0, 16); a0 += __shfl_xor(a0, 32);
  a1 += __shfl_xor(a1, 8); a1 += __shfl_xor(a1, 16); a1 += __shfl_xor(a1, 32);
  a2 += __shfl_xor(a2, 8); a2 += __shfl_xor(a2, 16); a2 += __shfl_xor(a2, 32);
  a3 += __shfl_xor(a3, 8); a3 += __shfl_xor(a3, 16); a3 += __shfl_xor(a3, 32);
  // self loop — AFTER fold
  {
    float lg = als_self + aldn + loopat[n] * ce;
    lg = (lg >= 0.f) ? lg : NEG_SLOPE * lg;
    float p = __expf(fminf(lg, 60.f));
    ssum += p;
    a0 = fmaf(p, s01.x, a0); a1 = fmaf(p, s01.y, a1);
    a2 = fmaf(p, s23.x, a2); a3 = fmaf(p, s23.y, a3);
  }
  if (oct == 0) {
    float inv = 1.0f / ssum;
    float4 b4 = ((const float4*)bias)[fidx];
    float4 g4 = ((const float4*)gamma)[fidx];
    float4 be4 = ((const float4*)beta)[fidx];
    float4 rm4 = ((const float4*)rm)[fidx];
    float4 rv4 = ((const float4*)rv)[fidx];
    float o0 = a0 * inv + b4.x, o1 = a1 * inv + b4.y;
    float o2 = a2 * inv + b4.z, o3 = a3 * inv + b4.w;
    o0 = (o0 - rm4.x) * (g4.x * rsqrtf(rv4.x + BN_EPS)) + be4.x;
    o1 = (o1 - rm4.y) * (g4.y * rsqrtf(rv4.y + BN_EPS)) + be4.y;
    o2 = (o2 - rm4.z) * (g4.z * rsqrtf(rv4.z + BN_EPS)) + be4.z;
    o3 = (o3 - rm4.w) * (g4.w * rsqrtf(rv4.w + BN_EPS)) + be4.w;
    o0 = (o0 > 0.f) ? o0 : expm1f(o0);
    o1 = (o1 > 0.f) ? o1 : expm1f(o1);
    o2 = (o2 > 0.f) ? o2 : expm1f(o2);
    o3 = (o3 > 0.f) ? o3 : expm1f(o3);
    int b = batch[n];
    float* pp = pool + (size_t)b * HIDDEN + H * 32 + 4 * i8;
    atomicAdd(pp + 0, o0);
    atomicAdd(pp + 1, o1);
    atomicAdd(pp + 2, o2);
    atomicAdd(pp + 3, o3);
    if (H == 0 && l == 0) atomicAdd(&cntg[b], 1);
  }
}

// ---------------- classifier ----------------
__global__ __launch_bounds__(640) void final_kernel(
    const float* __restrict__ pool, const int* __restrict__ cntg,
    const float* __restrict__ Wc, const float* __restrict__ bc,
    float* __restrict__ out) {
  int t = threadIdx.x;
  if (t >= NBATCH * NC) return;
  int b = t / NC, c = t - b * NC;
  float inv = 1.0f / fmaxf((float)cntg[b], 1.0f);
  float s = bc[c];
  #pragma unroll
  for (int d = 0; d < HIDDEN; ++d)
    s = fmaf(pool[b * HIDDEN + d] * inv, Wc[d * NC + c], s);
  out[t] = s;
}

extern "C" void kernel_launch(void* const* d_in, const int* in_sizes, int n_in,
                              void* d_out, int out_size, void* d_ws, size_t ws_size,
                              hipStream_t stream) {
  const float* x     = (const float*)d_in[0];
  const float* raw   = (const float*)d_in[1];
  const int*   ei    = (const int*)  d_in[2];
  const int*   batch = (const int*)  d_in[3];
  const float* W1    = (const float*)d_in[4];
  const float* asrc1 = (const float*)d_in[5];
  const float* adst1 = (const float*)d_in[6];
  const float* We1   = (const float*)d_in[7];
  const float* ae1   = (const float*)d_in[8];
  const float* b1    = (const float*)d_in[9];
  const float* g1    = (const float*)d_in[10];
  const float* be1   = (const float*)d_in[11];
  const float* rm1   = (const float*)d_in[12];
  const float* rv1   = (const float*)d_in[13];
  const float* W2    = (const float*)d_in[14];
  const float* asrc2 = (const float*)d_in[15];
  const float* adst2 = (const float*)d_in[16];
  const float* We2   = (const float*)d_in[17];
  const float* ae2   = (const float*)d_in[18];
  const float* b2    = (const float*)d_in[19];
  const float* g2    = (const float*)d_in[20];
  const float* be2   = (const float*)d_in[21];
  const float* rm2   = (const float*)d_in[22];
  const float* rv2   = (const float*)d_in[23];
  const float* Wc    = (const float*)d_in[24];
  const float* bc    = (const float*)d_in[25];
  float* out = (float*)d_out;

  char* ws = (char*)d_ws;
  size_t off = 0;
  auto alloc = [&](size_t bytes) -> void* {
    void* p = ws + off;
    off += bytes;
    off = (off + 255) & ~(size_t)255;
    return p;
  };
  float*    ea      = (float*)   alloc((size_t)N_EDGES * 4);
  float*    csr_ea  = (float*)   alloc((size_t)N_EDGES * 4);
  int*      csr_src = (int*)     alloc((size_t)N_EDGES * 4);
  float*    easum   = (float*)   alloc((size_t)N_NODES * 4);
  int*      cnt     = (int*)     alloc((size_t)N_NODES * 4);
  int*      cnt2    = (int*)     alloc((size_t)N_NODES * 4);
  int*      rowptr  = (int*)     alloc((size_t)(N_NODES + 1) * 4);
  float*    loopat  = (float*)   alloc((size_t)N_NODES * 4);
  ushort_t* tabLo1  = (ushort_t*)alloc((size_t)N_NODES * 32 * 2);   // 3.2 MB
  ushort_t* tabHi1  = (ushort_t*)alloc((size_t)N_NODES * 32 * 2);
  float*    als1    = (float*)   alloc((size_t)N_NODES * HEADS * 4);
  float*    ald1    = (float*)   alloc((size_t)N_NODES * HEADS * 4);
  float*    h2      = (float*)   alloc((size_t)N_NODES * GH * 4);
  ushort_t* tabLo2  = (ushort_t*)alloc((size_t)N_NODES * 32 * 2);
  ushort_t* tabHi2  = (ushort_t*)alloc((size_t)N_NODES * 32 * 2);
  float*    als2    = (float*)   alloc((size_t)N_NODES * 4);
  float*    ald2    = (float*)   alloc((size_t)N_NODES * 4);
  int*      bsum    = (int*)     alloc(64 * 4);
  float*    pool    = (float*)   alloc((size_t)NBATCH * HIDDEN * 4);
  int*      cntg    = (int*)     alloc((size_t)NBATCH * 4);

  hipMemsetAsync(easum, 0, (size_t)N_NODES * 4, stream);
  hipMemsetAsync(cnt,   0, (size_t)N_NODES * 4, stream);
  hipMemsetAsync(cnt2,  0, (size_t)N_NODES * 4, stream);
  hipMemsetAsync(pool,  0, (size_t)NBATCH * HIDDEN * 4, stream);
  hipMemsetAsync(cntg,  0, (size_t)NBATCH * 4, stream);

  int egrid = (N_EDGES + 255) / 256;
  edge_kernel<<<egrid, 256, 0, stream>>>(ei, raw, ea, easum, cnt);
  scan_part<<<NTILES, SCAN_TPB, 0, stream>>>(cnt, easum, rowptr, loopat, bsum);
  scan_top<<<1, 64, 0, stream>>>(bsum, rowptr);
  scan_add<<<NTILES, SCAN_TPB, 0, stream>>>(rowptr, bsum);
  scatter_kernel<<<egrid, 256, 0, stream>>>(ei, ea, rowptr, cnt2, csr_src, csr_ea);

  int cgrid = (N_NODES + 3) / 4;
  gemm1_kernel<<<1024, 256, 0, stream>>>(x, W1, asrc1, adst1, tabLo1, tabHi1, als1, ald1);
  conv1_half_kernel<<<cgrid, 256, 0, stream>>>(tabLo1, als1, ald1, We1, ae1,
      rowptr, csr_src, csr_ea, loopat, b1, g1, be1, rm1, rv1, h2, 0);
  conv1_half_kernel<<<cgrid, 256, 0, stream>>>(tabHi1, als1, ald1, We1, ae1,
      rowptr, csr_src, csr_ea, loopat, b1, g1, be1, rm1, rv1, h2, 1);
  gemm2_kernel<<<1024, 256, 0, stream>>>(h2, W2, asrc2, adst2, tabLo2, tabHi2, als2, ald2);
  conv2_half_kernel<<<cgrid, 256, 0, stream>>>(tabLo2, als2, ald2, We2, ae2,
      rowptr, csr_src, csr_ea, loopat, b2, g2, be2, rm2, rv2, batch, pool, cntg, 0);
  conv2_half_kernel<<<cgrid, 256, 0, stream>>>(tabHi2, als2, ald2, We2, ae2,
      rowptr, csr_src, csr_ea, loopat, b2, g2, be2, rm2, rv2, batch, pool, cntg, 1);
  final_kernel<<<1, 640, 0, stream>>>(pool, cntg, Wc, bc, out);
}